// Round 1
// baseline (146.174 us; speedup 1.0000x reference)
//
#include <hip/hip_runtime.h>
#include <math.h>

typedef float f32x4 __attribute__((ext_vector_type(4)));
typedef unsigned int u32x4 __attribute__((ext_vector_type(4)));
typedef short bf16x8 __attribute__((ext_vector_type(8)));

__device__ __forceinline__ unsigned f2bf1(float f) {
  unsigned u = __builtin_bit_cast(unsigned, f);
  return (u + 0x7FFFu + ((u >> 16) & 1u)) >> 16;
}
__device__ __forceinline__ unsigned pack2(float a, float b) {
  return f2bf1(a) | (f2bf1(b) << 16);
}

__device__ __forceinline__ f32x4 mfma16(u32x4 a, u32x4 b, f32x4 c) {
  return __builtin_amdgcn_mfma_f32_16x16x32_bf16(
      __builtin_bit_cast(bf16x8, a), __builtin_bit_cast(bf16x8, b), c, 0, 0, 0);
}

// Convert C/D accumulators of Z^T into A/B-layout bf16 fragments of Z.
// Input acc[s_tile][f_tile]: element r = Z^T[s_tile*16 + 4g + r][f_tile*16 + f]
// Output frag[f_tile][ks]: bf16 element j = Z[f_tile*16 + f][ks*32 + g*8 + j]
template <int NS, int NF, int NKS>
__device__ __forceinline__ void cvt_frags(const f32x4 (&acc)[NS][NF],
                                          u32x4 (&frag)[NF][NKS],
                                          int f, int g) {
  unsigned pk[NS][NF][2];
#pragma unroll
  for (int s = 0; s < NS; ++s)
#pragma unroll
    for (int n = 0; n < NF; ++n) {
      pk[s][n][0] = pack2(acc[s][n][0], acc[s][n][1]);
      pk[s][n][1] = pack2(acc[s][n][2], acc[s][n][3]);
    }
  const bool hi = ((g >> 1) & 1) != 0;
#pragma unroll
  for (int w = 0; w < 4; ++w) {
    const int gp = 2 * (g & 1) + (w >> 1);
    const int idx = (f + (gp << 4)) << 2;
#pragma unroll
    for (int n = 0; n < NF; ++n)
#pragma unroll
      for (int ks = 0; ks < NKS; ++ks) {
        int lo = __builtin_amdgcn_ds_bpermute(idx, (int)pk[2 * ks + 0][n][w & 1]);
        int h2 = __builtin_amdgcn_ds_bpermute(idx, (int)pk[2 * ks + 1][n][w & 1]);
        frag[n][ks][w] = (unsigned)(hi ? h2 : lo);
      }
  }
}

__launch_bounds__(256, 2)
__global__ void lwmh_kernel(const float* __restrict__ x,
                            const float* __restrict__ Wq,
                            const float* __restrict__ Wk,
                            const float* __restrict__ Wv,
                            float* __restrict__ out,
                            float* __restrict__ attw,
                            int nb) {
  const int lane = threadIdx.x & 63;
  const int f = lane & 15;
  const int g = lane >> 4;
  const int wid = blockIdx.x * (blockDim.x >> 6) + (threadIdx.x >> 6);
  const int nwaves = gridDim.x * (blockDim.x >> 6);

  // Resident W fragments. For Wq^T/Wk^T A-frags and Wv B-frags the per-lane
  // pattern is identical: frag[t][ks] elem j = Wm[ks*32+g*8+j][t*16+f].
  u32x4 wq[4][2], wk[4][2], wv[4][2];
  {
#pragma unroll
    for (int t = 0; t < 4; ++t)
#pragma unroll
      for (int ks = 0; ks < 2; ++ks) {
        const int off = (ks * 32 + g * 8) * 64 + t * 16 + f;
        const float* bq = Wq + off;
        const float* bk = Wk + off;
        const float* bv = Wv + off;
        u32x4 fq, fk, fv;
#pragma unroll
        for (int w = 0; w < 4; ++w) {
          fq[w] = pack2(bq[(2 * w) * 64], bq[(2 * w + 1) * 64]);
          fk[w] = pack2(bk[(2 * w) * 64], bk[(2 * w + 1) * 64]);
          fv[w] = pack2(bv[(2 * w) * 64], bv[(2 * w + 1) * 64]);
        }
        wq[t][ks] = fq;
        wk[t][ks] = fk;
        wv[t][ks] = fv;
      }
  }

  f32x4 xc[2][2][2], xn[2][2][2];

  auto loadX = [&](int b, f32x4 (&xr)[2][2][2]) {
    const float* xb = x + (size_t)b * 2048;
#pragma unroll
    for (int mt = 0; mt < 2; ++mt)
#pragma unroll
      for (int ks = 0; ks < 2; ++ks) {
        const float* p0 = xb + (mt * 16 + f) * 64 + ks * 32 + g * 8;
        xr[mt][ks][0] = *(const f32x4*)p0;
        xr[mt][ks][1] = *(const f32x4*)(p0 + 4);
      }
  };

  int b = wid;
  if (b < nb) loadX(b, xc);

  for (; b < nb; b += nwaves) {
    const int bn = b + nwaves;

    // x -> bf16 A-frags (also serve as B-frags of X^T).
    u32x4 xf[2][2];
#pragma unroll
    for (int mt = 0; mt < 2; ++mt)
#pragma unroll
      for (int ks = 0; ks < 2; ++ks) {
        u32x4 fr;
        fr[0] = pack2(xc[mt][ks][0][0], xc[mt][ks][0][1]);
        fr[1] = pack2(xc[mt][ks][0][2], xc[mt][ks][0][3]);
        fr[2] = pack2(xc[mt][ks][1][0], xc[mt][ks][1][1]);
        fr[3] = pack2(xc[mt][ks][1][2], xc[mt][ks][1][3]);
        xf[mt][ks] = fr;
      }

    if (bn < nb) loadX(bn, xn);  // prefetch next block

    // Q^T = Wq^T @ X^T   (C/D: col=t in lane&15, row=h spread)
    f32x4 qt[4][2];
#pragma unroll
    for (int mh = 0; mh < 4; ++mh)
#pragma unroll
      for (int nt = 0; nt < 2; ++nt) {
        f32x4 a = {0.f, 0.f, 0.f, 0.f};
#pragma unroll
        for (int ks = 0; ks < 2; ++ks) a = mfma16(wq[mh][ks], xf[nt][ks], a);
        qt[mh][nt] = a;
      }
    u32x4 aQ[2][2];
    cvt_frags<4, 2, 2>(qt, aQ, f, g);

    // K^T = Wk^T @ X^T
    f32x4 kt[4][2];
#pragma unroll
    for (int mh = 0; mh < 4; ++mh)
#pragma unroll
      for (int nt = 0; nt < 2; ++nt) {
        f32x4 a = {0.f, 0.f, 0.f, 0.f};
#pragma unroll
        for (int ks = 0; ks < 2; ++ks) a = mfma16(wk[mh][ks], xf[nt][ks], a);
        kt[mh][nt] = a;
      }
    u32x4 aK[2][2];
    cvt_frags<4, 2, 2>(kt, aK, f, g);

    // V = X @ Wv   (C/D: col=h in lane&15, row=s spread)
    f32x4 va[2][4];
#pragma unroll
    for (int ms = 0; ms < 2; ++ms)
#pragma unroll
      for (int nh = 0; nh < 4; ++nh) {
        f32x4 a = {0.f, 0.f, 0.f, 0.f};
#pragma unroll
        for (int ks = 0; ks < 2; ++ks) a = mfma16(xf[ms][ks], wv[nh][ks], a);
        va[ms][nh] = a;
      }
    u32x4 bV[4][1];
    cvt_frags<2, 4, 1>(va, bV, f, g);

    // S^T = K @ Q^T  (C/D: col=t in lane&15, row=s spread)
    f32x4 st[2][2];
#pragma unroll
    for (int ms = 0; ms < 2; ++ms)
#pragma unroll
      for (int nt = 0; nt < 2; ++nt) {
        f32x4 a = {0.f, 0.f, 0.f, 0.f};
#pragma unroll
        for (int ks = 0; ks < 2; ++ks) a = mfma16(aK[ms][ks], aQ[nt][ks], a);
        st[ms][nt] = a;
      }

    // masked softmax over s for each t. lane holds t = nt*16+f, s = ms*16+4g+r
    float pe[2][2][4];
#pragma unroll
    for (int nt = 0; nt < 2; ++nt) {
      const int t = nt * 16 + f;
      float m = -INFINITY;
#pragma unroll
      for (int ms = 0; ms < 2; ++ms)
#pragma unroll
        for (int r = 0; r < 4; ++r) {
          const int s = ms * 16 + 4 * g + r;
          float v = st[ms][nt][r] * 0.125f;
          v = (t >= s && (t - s) <= 7) ? v : -INFINITY;
          pe[ms][nt][r] = v;
          m = fmaxf(m, v);
        }
      m = fmaxf(m, __shfl_xor(m, 16));
      m = fmaxf(m, __shfl_xor(m, 32));
      float sum = 0.f;
#pragma unroll
      for (int ms = 0; ms < 2; ++ms)
#pragma unroll
        for (int r = 0; r < 4; ++r) {
          const float e = __expf(pe[ms][nt][r] - m);
          pe[ms][nt][r] = e;
          sum += e;
        }
      sum += __shfl_xor(sum, 16);
      sum += __shfl_xor(sum, 32);
      const float inv = 1.0f / sum;
#pragma unroll
      for (int ms = 0; ms < 2; ++ms)
#pragma unroll
        for (int r = 0; r < 4; ++r) pe[ms][nt][r] *= inv;
    }

    // write attention weights (fp32), P^T layout scatter; L2 write-combines
    {
      float* aw = attw + (size_t)b * 1024;
#pragma unroll
      for (int ms = 0; ms < 2; ++ms)
#pragma unroll
        for (int nt = 0; nt < 2; ++nt)
#pragma unroll
          for (int r = 0; r < 4; ++r)
            aw[(nt * 16 + f) * 32 + ms * 16 + 4 * g + r] = pe[ms][nt][r];
    }

    // P -> bf16 A-frags
    f32x4 pacc[2][2];
#pragma unroll
    for (int ms = 0; ms < 2; ++ms)
#pragma unroll
      for (int nt = 0; nt < 2; ++nt) {
        f32x4 a;
        a[0] = pe[ms][nt][0];
        a[1] = pe[ms][nt][1];
        a[2] = pe[ms][nt][2];
        a[3] = pe[ms][nt][3];
        pacc[ms][nt] = a;
      }
    u32x4 aP[2][1];
    cvt_frags<2, 2, 1>(pacc, aP, f, g);

    // O = P @ V  (C/D: col=h in lane&15, row=t spread)
    f32x4 o[2][4];
#pragma unroll
    for (int mt = 0; mt < 2; ++mt)
#pragma unroll
      for (int nh = 0; nh < 4; ++nh) {
        f32x4 a = {0.f, 0.f, 0.f, 0.f};
        o[mt][nh] = mfma16(aP[mt][0], bV[nh][0], a);
      }

    {
      float* op = out + (size_t)b * 2048;
#pragma unroll
      for (int mt = 0; mt < 2; ++mt)
#pragma unroll
        for (int nh = 0; nh < 4; ++nh)
#pragma unroll
          for (int r = 0; r < 4; ++r)
            op[(mt * 16 + 4 * g + r) * 64 + nh * 16 + f] = o[mt][nh][r];
    }

    // rotate prefetch buffer
    if (bn < nb) {
#pragma unroll
      for (int mt = 0; mt < 2; ++mt)
#pragma unroll
        for (int ks = 0; ks < 2; ++ks) {
          xc[mt][ks][0] = xn[mt][ks][0];
          xc[mt][ks][1] = xn[mt][ks][1];
        }
    }
  }
}

extern "C" void kernel_launch(void* const* d_in, const int* in_sizes, int n_in,
                              void* d_out, int out_size, void* d_ws, size_t ws_size,
                              hipStream_t stream) {
  const float* x = (const float*)d_in[0];
  const float* Wq = (const float*)d_in[1];
  const float* Wk = (const float*)d_in[2];
  const float* Wv = (const float*)d_in[3];
  const int nb = in_sizes[0] / 2048;  // batch blocks of 32x64
  float* out = (float*)d_out;
  float* attw = out + (size_t)nb * 2048;

  const int grid = 1024;  // 4096 waves, grid-stride over nb blocks
  lwmh_kernel<<<grid, 256, 0, stream>>>(x, Wq, Wk, Wv, out, attw, nb);
}